// Round 4
// baseline (907.488 us; speedup 1.0000x reference)
//
#include <hip/hip_runtime.h>
#include <hip/hip_bf16.h>

#define NCN 10000   // computation nodes
#define ECN 120000  // computation edges
#define NHH 256     // hidden
#define CEE 16      // cedge feat dim  (CF,CE = 64,16 !)
#define GCN 100     // cgroups
#define GSZ 100     // nodes per cgroup
#define NTT 16      // topo nodes
#define ETT 64      // topo edges
#define TGG 8       // tgroups
#define OPEE 4
#define CFF 64
#define TFF 32
#define TEE 16
#define NPB 8       // dst nodes per block in fused layer kernels

// ---------- static device scratch (no d_ws dependency) ----------
__device__ int   g_indeg[NCN];
__device__ int   g_outdeg[NCN];
__device__ int   g_cursor[NCN];
__device__ int   g_off[NCN+1];
__device__ int   g_eid[ECN];
__device__ int   g_srcarr[ECN];
__device__ float g_onorm[NCN];
__device__ float g_inorm[NCN];
__device__ float g_eagg [NCN*CEE];
__device__ float g_eaggR[NCN*CEE];
__device__ float g_relut[TGG*NHH];
__device__ float g_v0p[TGG*NHH];
__device__ float g_v0[NHH];
__device__ float g_x0[(size_t)NCN*NHH];
__device__ float g_x1[(size_t)NCN*NHH];
__device__ float g_cemb[GCN*NHH];

__device__ __forceinline__ int clampi(int v,int lo,int hi){ return v<lo?lo:(v>hi?hi:v); }

// diagnostic: on input-size mismatch write 1e6+idx so absmax reveals the index
__global__ __launch_bounds__(256) void k_badsize(float* out, int n, float code){
    int i = blockIdx.x*256 + threadIdx.x;
    if (i < n) out[i] = code;
}

// ---------------- graph prep ----------------
__global__ __launch_bounds__(256) void k_zero3(){
    int i = blockIdx.x*256 + threadIdx.x;
    if (i < NCN){ g_indeg[i]=0; g_outdeg[i]=0; g_cursor[i]=0; }
}

__global__ __launch_bounds__(256) void k_degrees(const int* __restrict__ src, const int* __restrict__ dst){
    int e = blockIdx.x*256 + threadIdx.x;
    if (e < ECN){
        atomicAdd(&g_outdeg[clampi(src[e],0,NCN-1)],1);
        atomicAdd(&g_indeg [clampi(dst[e],0,NCN-1)],1);
    }
}

__global__ __launch_bounds__(256) void k_norms(){
    int i = blockIdx.x*256 + threadIdx.x;
    if (i < NCN){
        g_onorm[i] = rsqrtf((float)max(g_outdeg[i],1));
        g_inorm[i] = rsqrtf((float)max(g_indeg[i],1));
    }
}

// exclusive scan of indeg -> off[0..NCN]
__global__ __launch_bounds__(1024) void k_scan(){
    __shared__ int cs[1024];
    const int CH = (NCN + 1023)/1024;  // 10
    int t = threadIdx.x;
    int base = t*CH;
    int s = 0;
    for (int j=0;j<CH;j++){ int idx=base+j; if (idx<NCN) s += g_indeg[idx]; }
    cs[t] = s; __syncthreads();
    for (int ofs=1; ofs<1024; ofs<<=1){
        int v = (t>=ofs) ? cs[t-ofs] : 0;
        __syncthreads();
        cs[t] += v;
        __syncthreads();
    }
    int run = (t==0) ? 0 : cs[t-1];
    for (int j=0;j<CH;j++){
        int idx = base+j;
        if (idx <= NCN) g_off[idx] = run;
        if (idx < NCN) run += g_indeg[idx];
    }
}

__global__ __launch_bounds__(256) void k_scatter(const int* __restrict__ dst){
    int e = blockIdx.x*256 + threadIdx.x;
    if (e < ECN){
        int d = clampi(dst[e],0,NCN-1);
        int pos = g_off[d] + atomicAdd(&g_cursor[d],1);
        g_eid[clampi(pos,0,ECN-1)] = e;
    }
}

// per-node insertion sort by eid (deterministic edge order) + fill src ids
__global__ __launch_bounds__(256) void k_sortfill(const int* __restrict__ c_src){
    int d = blockIdx.x*256 + threadIdx.x;
    if (d < NCN){
        int b = clampi(g_off[d],0,ECN), e = clampi(g_off[d+1],b,ECN);
        for (int i=b+1;i<e;i++){
            int key = g_eid[i]; int j = i-1;
            while (j>=b && g_eid[j]>key){ g_eid[j+1]=g_eid[j]; j--; }
            g_eid[j+1] = key;
        }
        for (int i=b;i<e;i++) g_srcarr[i] = clampi(c_src[clampi(g_eid[i],0,ECN-1)],0,NCN-1);
    }
}

// eagg[d][f] = sum efeat, eaggR[d][f] = sum relu(efeat)  (layer-invariant)
__global__ __launch_bounds__(256) void k_eagg(const float* __restrict__ ef){
    int d = blockIdx.x*16 + threadIdx.x/16;
    int f = threadIdx.x%16;
    if (d < NCN){
        float s=0.f, sr=0.f;
        int b=clampi(g_off[d],0,ECN), e=clampi(g_off[d+1],b,ECN);
        for (int i=b;i<e;i++){
            float v = ef[(size_t)clampi(g_eid[i],0,ECN-1)*CEE + f];
            s += v; sr += fmaxf(v,0.f);
        }
        g_eagg [(size_t)d*CEE+f] = s;
        g_eaggR[(size_t)d*CEE+f] = sr;
    }
}

// ---------------- topology GNN (one block) ----------------
__global__ __launch_bounds__(256) void k_topo(
    const float* __restrict__ tfeats, const float* __restrict__ tef,
    const float* __restrict__ tW0, const float* __restrict__ tb0,
    const float* __restrict__ tWr, const float* __restrict__ tbr,
    const int* __restrict__ t_src, const int* __restrict__ t_dst,
    const int* __restrict__ tgroups)
{
    __shared__ float x[NTT][NHH];
    __shared__ float h[NTT][NHH+TEE];
    __shared__ float onorm[NTT], inorm[NTT];
    __shared__ int sdeg[2*NTT];
    __shared__ int ssrc[ETT], sdst[ETT];
    const int t = threadIdx.x;

    if (t < 2*NTT) sdeg[t]=0;
    __syncthreads();
    if (t < ETT){
        int s=clampi(t_src[t],0,NTT-1), d=clampi(t_dst[t],0,NTT-1);
        ssrc[t]=s; sdst[t]=d;
        atomicAdd(&sdeg[s],1); atomicAdd(&sdeg[NTT+d],1);
    }
    __syncthreads();
    if (t < NTT){
        onorm[t]=rsqrtf((float)max(sdeg[t],1));
        inorm[t]=rsqrtf((float)max(sdeg[NTT+t],1));
    }
    __syncthreads();

    // ----- layer 0: in=48 (32 tfeats + 16 tef), double_act, relu_out -----
    for (int i=t;i<NTT*48;i+=256) h[i/48][i%48]=0.f;
    __syncthreads();
    if (t < 48){
        for (int e=0;e<ETT;e++){
            int s=ssrc[e], d=sdst[e];
            float v = (t<TFF) ? tfeats[s*TFF+t]*onorm[s]
                              : tef[e*TEE+(t-TFF)];
            h[d][t] += fmaxf(v,0.f);
        }
    }
    __syncthreads();
    {
        float acc[NTT];
        #pragma unroll
        for (int n=0;n<NTT;n++) acc[n]=0.f;
        for (int k=0;k<48;k++){
            float w=tW0[k*NHH+t];
            #pragma unroll
            for (int n=0;n<NTT;n++) acc[n]+=h[n][k]*w;
        }
        float b=tb0[t];
        #pragma unroll
        for (int n=0;n<NTT;n++) x[n][t]=fmaxf(acc[n]*inorm[n]+b,0.f);
    }
    __syncthreads();

    // ----- layers 1..3 (tWr[0..2]), in = 256+16 -----
    for (int L=0;L<3;L++){
        const float* W  = tWr + (size_t)L*(NHH+TEE)*NHH;
        const float* bb = tbr + L*NHH;
        #pragma unroll
        for (int n=0;n<NTT;n++) x[n][t]*=onorm[n];     // column t owned by thread t
        for (int i=t;i<NTT*(NHH+TEE);i+=256) h[i/(NHH+TEE)][i%(NHH+TEE)]=0.f;
        __syncthreads();
        for (int e=0;e<ETT;e++){
            int s=ssrc[e], d=sdst[e];
            h[d][t]+=x[s][t];
            if (t<TEE) h[d][NHH+t]+=tef[e*TEE+t];
        }
        __syncthreads();
        float acc[NTT];
        #pragma unroll
        for (int n=0;n<NTT;n++) acc[n]=0.f;
        for (int k=0;k<NHH+TEE;k++){
            float w=W[(size_t)k*NHH+t];
            #pragma unroll
            for (int n=0;n<NTT;n++) acc[n]+=h[n][k]*w;
        }
        float b=bb[t];
        #pragma unroll
        for (int n=0;n<NTT;n++){
            float val=acc[n]*inorm[n]+b;
            x[n][t] = (L<2) ? (x[n][t]+fmaxf(val,0.f)) : val;
        }
        __syncthreads();
    }
    // t_emb (group sums of 2), then relu (folds out of cGNN layer-0 double_act since out_norm>0)
    for (int g=0; g<TGG; g++){
        int i0=clampi(tgroups[g*2+0],0,NTT-1), i1=clampi(tgroups[g*2+1],0,NTT-1);
        g_relut[g*NHH+t]=fmaxf(x[i0][t]+x[i1][t],0.f);
    }
}

// v0[c] = sum_j relu_t[j] * cW0[68+j][c]  (collapsed broadcast GEMV, deterministic split)
__global__ __launch_bounds__(256) void k_v0(const float* __restrict__ cW0){
    int b=blockIdx.x, c=threadIdx.x;
    const float* Wm = cW0 + (size_t)(CFF+OPEE + b*NHH)*NHH;
    const float* rt = g_relut + b*NHH;
    float acc=0.f;
    for (int j=0;j<NHH;j++) acc += rt[j]*Wm[(size_t)j*NHH+c];
    g_v0p[b*NHH+c]=acc;
}
__global__ __launch_bounds__(256) void k_v0r(){
    int c=threadIdx.x;
    float s=0.f;
    for (int b=0;b<TGG;b++) s+=g_v0p[b*NHH+c];
    g_v0[c]=s;
}

// ---------------- cGNN layer 0 (fused gather + GEMM) ----------------
// feat row layout of cW0: [0:64] cfeats | [64:68] opemb | [68:2116] t_flat | [2116:2132] cedge
__global__ __launch_bounds__(256) void k_l0(
    const int* __restrict__ ctypes,
    const float* __restrict__ cfeats, const float* __restrict__ opemb,
    const float* __restrict__ cW0, const float* __restrict__ cb0)
{
    __shared__ float sh[NPB][72];    // [node][k: 0..63 cfeats, 64..67 opemb, 68 s_on]
    __shared__ float se[NPB][CEE];
    int d0=blockIdx.x*NPB, t=threadIdx.x;
    if (t < NPB*CEE){ int n=t/CEE,k=t%CEE; se[n][k]=g_eaggR[(size_t)(d0+n)*CEE+k]; }
    int g=t/72, k=t%72;
    if (g<3){
        for (int n=g;n<NPB;n+=3){
            int d=d0+n;
            int b=clampi(g_off[d],0,ECN), e=clampi(g_off[d+1],b,ECN);
            float acc=0.f;
            for (int i=b;i<e;i++){
                int s=g_srcarr[i];
                float on=g_onorm[s];
                float v;
                if (k<CFF)            v=fmaxf(cfeats[(size_t)s*CFF+k],0.f);
                else if (k<CFF+OPEE)  v=fmaxf(opemb[clampi(ctypes[s],0,255)*OPEE+(k-CFF)],0.f);
                else                  v=(k==68)?1.f:0.f;
                acc += v*on;
            }
            sh[n][k]=acc;
        }
    }
    __syncthreads();
    float acc[NPB];
    #pragma unroll
    for (int n=0;n<NPB;n++) acc[n]=0.f;
    for (int kk=0;kk<CFF+OPEE;kk++){
        float w=cW0[(size_t)kk*NHH+t];
        #pragma unroll
        for (int n=0;n<NPB;n++) acc[n]+=sh[n][kk]*w;
    }
    {
        float w=g_v0[t];
        #pragma unroll
        for (int n=0;n<NPB;n++) acc[n]+=sh[n][68]*w;   // s_on * v0 (collapsed t_flat block)
    }
    const float* We = cW0 + (size_t)(CFF+OPEE+TGG*NHH)*NHH;
    #pragma unroll
    for (int kk=0;kk<CEE;kk++){
        float w=We[(size_t)kk*NHH+t];
        #pragma unroll
        for (int n=0;n<NPB;n++) acc[n]+=se[n][kk]*w;
    }
    float bb=cb0[t];
    #pragma unroll
    for (int n=0;n<NPB;n++){
        int d=d0+n;
        g_x0[(size_t)d*NHH+t]=fmaxf(acc[n]*g_inorm[d]+bb,0.f);
    }
}

// ---------------- recurrent layers (fused gather + GEMM, ping-pong via template) ----------------
template<int DIR>   // DIR=0: x0->x1, DIR=1: x1->x0
__global__ __launch_bounds__(256) void k_layer(
    const float* __restrict__ W, const float* __restrict__ bias, int relu_res)
{
    const float* xin  = DIR ? g_x1 : g_x0;
    float*       xout = DIR ? g_x0 : g_x1;
    __shared__ float sh[NPB][NHH];
    __shared__ float se[NPB][CEE];
    int d0=blockIdx.x*NPB, t=threadIdx.x;
    if (t < NPB*CEE){ int n=t/CEE,k=t%CEE; se[n][k]=g_eagg[(size_t)(d0+n)*CEE+k]; }
    for (int n=0;n<NPB;n++){
        int d=d0+n;
        int b=clampi(g_off[d],0,ECN), e=clampi(g_off[d+1],b,ECN);
        float acc=0.f;
        for (int i=b;i<e;i++){
            int s=g_srcarr[i];
            acc += xin[(size_t)s*NHH+t]*g_onorm[s];
        }
        sh[n][t]=acc;
    }
    __syncthreads();
    float acc[NPB];
    #pragma unroll
    for (int n=0;n<NPB;n++) acc[n]=0.f;
    #pragma unroll 4
    for (int k=0;k<NHH;k++){
        float w=W[(size_t)k*NHH+t];
        #pragma unroll
        for (int n=0;n<NPB;n++) acc[n]+=sh[n][k]*w;
    }
    #pragma unroll
    for (int k=0;k<CEE;k++){
        float w=W[(size_t)(NHH+k)*NHH+t];
        #pragma unroll
        for (int n=0;n<NPB;n++) acc[n]+=se[n][k]*w;
    }
    float bb=bias[t];
    #pragma unroll
    for (int n=0;n<NPB;n++){
        int d=d0+n;
        float val=acc[n]*g_inorm[d]+bb;
        float y = relu_res ? (xin[(size_t)d*NHH+t]*g_onorm[d] + fmaxf(val,0.f)) : val;
        xout[(size_t)d*NHH+t]=y;
    }
}

// ---------------- pooling + heads ----------------
__global__ __launch_bounds__(256) void k_cemb(const int* __restrict__ cgroups){
    int g=blockIdx.x, c=threadIdx.x;
    float s=0.f;
    for (int i=0;i<GSZ;i++){
        int idx=clampi(cgroups[g*GSZ+i],0,NCN-1);
        s += g_x1[(size_t)idx*NHH+c];
    }
    g_cemb[g*NHH+c]=s;
}

__global__ __launch_bounds__(256) void k_heads(
    const float* __restrict__ sW, const float* __restrict__ sb,
    const float* __restrict__ nW, const float* __restrict__ nb, float* __restrict__ out)
{
    __shared__ float red[256];
    __shared__ float z[9];
    int g=blockIdx.x, t=threadIdx.x;
    float e = g_cemb[(size_t)g*NHH+t];
    for (int j=0;j<9;j++){
        float w = (j==0) ? nW[t] : sW[t*TGG+(j-1)];
        red[t]=e*w; __syncthreads();
        for (int s=128;s>0;s>>=1){ if (t<s) red[t]+=red[t+s]; __syncthreads(); }
        if (t==0) z[j]=red[0];
        __syncthreads();
    }
    if (t==0){
        float z0 = z[0] + nb[0];
        float lsig = fminf(z0,0.f) - log1pf(expf(-fabsf(z0)));
        out[g*9+0]=lsig;
        float zz[8]; float m=-1e30f;
        for (int j=0;j<8;j++){ zz[j]=z[j+1]+sb[j]; m=fmaxf(m,zz[j]); }
        float s=0.f;
        for (int j=0;j<8;j++) s+=expf(zz[j]-m);
        float lse=m+logf(s);
        for (int j=0;j<8;j++) out[g*9+1+j]=zz[j]-lse;
    }
}

extern "C" void kernel_launch(void* const* d_in, const int* in_sizes, int n_in,
                              void* d_out, int out_size, void* d_ws, size_t ws_size,
                              hipStream_t stream) {
    // expected element counts (verified against reference shape comments)
    const int expect[24] = {
        NCN*CFF,              // cfeats      640000
        ECN*CEE,              // cedge_feats 1920000
        NTT*TFF,              // tfeats      512
        ETT*TEE,              // tedge_feats 1024
        256*OPEE,             // op_emb      1024
        (TFF+TEE)*NHH,        // tW0         12288
        NHH,                  // tb0
        3*(NHH+TEE)*NHH,      // tWr         208896
        3*NHH,                // tbr
        (CFF+OPEE+TGG*NHH+CEE)*NHH, // cW0   545792
        NHH,                  // cb0
        5*(NHH+CEE)*NHH,      // cWr         348160
        5*NHH,                // cbr
        NHH*TGG,              // sW
        TGG,                  // sb
        NHH,                  // nW
        1,                    // nb
        NCN, ECN, ECN, ETT, ETT,
        GCN*GSZ,              // cgroups
        TGG*2                 // tgroups
    };
    if (n_in < 24){
        k_badsize<<<(out_size+255)/256,256,0,stream>>>((float*)d_out, out_size, 2.0e6f);
        return;
    }
    for (int i=0;i<24;i++){
        if (in_sizes[i] != expect[i]){
            k_badsize<<<(out_size+255)/256,256,0,stream>>>((float*)d_out, out_size, 1.0e6f+(float)i);
            return;
        }
    }

    const float* cfeats = (const float*)d_in[0];
    const float* cef    = (const float*)d_in[1];
    const float* tfeats = (const float*)d_in[2];
    const float* tef    = (const float*)d_in[3];
    const float* opemb  = (const float*)d_in[4];
    const float* tW0    = (const float*)d_in[5];
    const float* tb0    = (const float*)d_in[6];
    const float* tWr    = (const float*)d_in[7];
    const float* tbr    = (const float*)d_in[8];
    const float* cW0    = (const float*)d_in[9];
    const float* cb0    = (const float*)d_in[10];
    const float* cWr    = (const float*)d_in[11];
    const float* cbr    = (const float*)d_in[12];
    const float* sW     = (const float*)d_in[13];
    const float* sb     = (const float*)d_in[14];
    const float* nW     = (const float*)d_in[15];
    const float* nb     = (const float*)d_in[16];
    const int* ctypes   = (const int*)d_in[17];
    const int* c_src    = (const int*)d_in[18];
    const int* c_dst    = (const int*)d_in[19];
    const int* t_src    = (const int*)d_in[20];
    const int* t_dst    = (const int*)d_in[21];
    const int* cgroups  = (const int*)d_in[22];
    const int* tgroups  = (const int*)d_in[23];

    const int EB = (ECN+255)/256, NB = (NCN+255)/256;

    k_zero3   <<<NB, 256, 0, stream>>>();
    k_degrees <<<EB, 256, 0, stream>>>(c_src, c_dst);
    k_norms   <<<NB, 256, 0, stream>>>();
    k_scan    <<<1, 1024, 0, stream>>>();
    k_scatter <<<EB, 256, 0, stream>>>(c_dst);
    k_sortfill<<<NB, 256, 0, stream>>>(c_src);
    k_eagg    <<<(NCN+15)/16, 256, 0, stream>>>(cef);

    k_topo    <<<1, 256, 0, stream>>>(tfeats, tef, tW0, tb0, tWr, tbr, t_src, t_dst, tgroups);
    k_v0      <<<TGG, 256, 0, stream>>>(cW0);
    k_v0r     <<<1, 256, 0, stream>>>();

    k_l0      <<<NCN/NPB, 256, 0, stream>>>(ctypes, cfeats, opemb, cW0, cb0);

    // 5 recurrent layers: x0 -> x1 -> x0 -> x1 -> x0 -> x1  (final in g_x1)
    k_layer<0><<<NCN/NPB, 256, 0, stream>>>(cWr + (size_t)0*(NHH+CEE)*NHH, cbr + 0*NHH, 1);
    k_layer<1><<<NCN/NPB, 256, 0, stream>>>(cWr + (size_t)1*(NHH+CEE)*NHH, cbr + 1*NHH, 1);
    k_layer<0><<<NCN/NPB, 256, 0, stream>>>(cWr + (size_t)2*(NHH+CEE)*NHH, cbr + 2*NHH, 1);
    k_layer<1><<<NCN/NPB, 256, 0, stream>>>(cWr + (size_t)3*(NHH+CEE)*NHH, cbr + 3*NHH, 1);
    k_layer<0><<<NCN/NPB, 256, 0, stream>>>(cWr + (size_t)4*(NHH+CEE)*NHH, cbr + 4*NHH, 0);

    k_cemb <<<GCN, 256, 0, stream>>>(cgroups);
    k_heads<<<GCN, 256, 0, stream>>>(sW, sb, nW, nb, (float*)d_out);
}

// Round 5
// 560.423 us; speedup vs baseline: 1.6193x; 1.6193x over previous
//
#include <hip/hip_runtime.h>
#include <hip/hip_bf16.h>

#define NCN 10000   // computation nodes
#define ECN 120000  // computation edges
#define NHH 256     // hidden
#define CEE 16      // cedge feat dim  (CF,CE = 64,16)
#define GCN 100     // cgroups
#define GSZ 100     // nodes per cgroup
#define NTT 16      // topo nodes
#define ETT 64      // topo edges
#define TGG 8       // tgroups
#define OPEE 4
#define CFF 64
#define TFF 32
#define TEE 16
#define NPB 8       // dst nodes per block in fused layer kernels

// ---------- static device scratch (no d_ws dependency) ----------
__device__ int   g_indeg[NCN];
__device__ int   g_outdeg[NCN];
__device__ int   g_cursor[NCN];
__device__ int   g_off[NCN+1];
__device__ int   g_eid[ECN];
__device__ int   g_srcarr[ECN];
__device__ float g_onorm[NCN];
__device__ float g_inorm[NCN];
__device__ float g_eagg [NCN*CEE];
__device__ float g_eaggR[NCN*CEE];
__device__ float g_relut[TGG*NHH];
__device__ float g_v0p[TGG*NHH];
__device__ float g_v0[NHH];
__device__ float g_x0[(size_t)NCN*NHH];
__device__ float g_x1[(size_t)NCN*NHH];
__device__ float g_cemb[GCN*NHH];

__device__ __forceinline__ int clampi(int v,int lo,int hi){ return v<lo?lo:(v>hi?hi:v); }

// diagnostic: on input-size mismatch write 1e6+idx so absmax reveals the index
__global__ __launch_bounds__(256) void k_badsize(float* out, int n, float code){
    int i = blockIdx.x*256 + threadIdx.x;
    if (i < n) out[i] = code;
}

// ---------------- graph prep ----------------
__global__ __launch_bounds__(256) void k_zero3(){
    int i = blockIdx.x*256 + threadIdx.x;
    if (i < NCN){ g_indeg[i]=0; g_outdeg[i]=0; g_cursor[i]=0; }
}

__global__ __launch_bounds__(256) void k_degrees(const int* __restrict__ src, const int* __restrict__ dst){
    int e = blockIdx.x*256 + threadIdx.x;
    if (e < ECN){
        atomicAdd(&g_outdeg[clampi(src[e],0,NCN-1)],1);
        atomicAdd(&g_indeg [clampi(dst[e],0,NCN-1)],1);
    }
}

__global__ __launch_bounds__(256) void k_norms(){
    int i = blockIdx.x*256 + threadIdx.x;
    if (i < NCN){
        g_onorm[i] = rsqrtf((float)max(g_outdeg[i],1));
        g_inorm[i] = rsqrtf((float)max(g_indeg[i],1));
    }
}

// exclusive scan of indeg -> off[0..NCN]
__global__ __launch_bounds__(1024) void k_scan(){
    __shared__ int cs[1024];
    const int CH = (NCN + 1023)/1024;  // 10
    int t = threadIdx.x;
    int base = t*CH;
    int s = 0;
    for (int j=0;j<CH;j++){ int idx=base+j; if (idx<NCN) s += g_indeg[idx]; }
    cs[t] = s; __syncthreads();
    for (int ofs=1; ofs<1024; ofs<<=1){
        int v = (t>=ofs) ? cs[t-ofs] : 0;
        __syncthreads();
        cs[t] += v;
        __syncthreads();
    }
    int run = (t==0) ? 0 : cs[t-1];
    for (int j=0;j<CH;j++){
        int idx = base+j;
        if (idx <= NCN) g_off[idx] = run;
        if (idx < NCN) run += g_indeg[idx];
    }
}

__global__ __launch_bounds__(256) void k_scatter(const int* __restrict__ dst){
    int e = blockIdx.x*256 + threadIdx.x;
    if (e < ECN){
        int d = clampi(dst[e],0,NCN-1);
        int pos = g_off[d] + atomicAdd(&g_cursor[d],1);
        g_eid[clampi(pos,0,ECN-1)] = e;
    }
}

// per-node insertion sort by eid (deterministic edge order) + fill src ids
__global__ __launch_bounds__(256) void k_sortfill(const int* __restrict__ c_src){
    int d = blockIdx.x*256 + threadIdx.x;
    if (d < NCN){
        int b = clampi(g_off[d],0,ECN), e = clampi(g_off[d+1],b,ECN);
        for (int i=b+1;i<e;i++){
            int key = g_eid[i]; int j = i-1;
            while (j>=b && g_eid[j]>key){ g_eid[j+1]=g_eid[j]; j--; }
            g_eid[j+1] = key;
        }
        for (int i=b;i<e;i++) g_srcarr[i] = clampi(c_src[clampi(g_eid[i],0,ECN-1)],0,NCN-1);
    }
}

// eagg[d][f] = sum efeat, eaggR[d][f] = sum relu(efeat)  (layer-invariant)
__global__ __launch_bounds__(256) void k_eagg(const float* __restrict__ ef){
    int d = blockIdx.x*16 + threadIdx.x/16;
    int f = threadIdx.x%16;
    if (d < NCN){
        float s=0.f, sr=0.f;
        int b=clampi(g_off[d],0,ECN), e=clampi(g_off[d+1],b,ECN);
        for (int i=b;i<e;i++){
            float v = ef[(size_t)clampi(g_eid[i],0,ECN-1)*CEE + f];
            s += v; sr += fmaxf(v,0.f);
        }
        g_eagg [(size_t)d*CEE+f] = s;
        g_eaggR[(size_t)d*CEE+f] = sr;
    }
}

// ---------------- topology GNN (one block, 1024 threads, split-K by quarter) ----------------
__global__ __launch_bounds__(1024) void k_topo(
    const float* __restrict__ tfeats, const float* __restrict__ tef,
    const float* __restrict__ tW0, const float* __restrict__ tb0,
    const float* __restrict__ tWr, const float* __restrict__ tbr,
    const int* __restrict__ t_src, const int* __restrict__ t_dst,
    const int* __restrict__ tgroups)
{
    __shared__ float x[NTT][NHH];          // 16 KB
    __shared__ float h[NTT][NHH+TEE];      // 17.4 KB
    __shared__ float part[4][NTT][NHH];    // 64 KB
    __shared__ float onorm[NTT], inorm[NTT];
    __shared__ int sdeg[2*NTT];
    __shared__ int ssrc[ETT], sdst[ETT];
    const int t = threadIdx.x;
    const int c = t & 255, q = t >> 8;     // column, K-quarter

    if (t < 2*NTT) sdeg[t]=0;
    __syncthreads();
    if (t < ETT){
        int s=clampi(t_src[t],0,NTT-1), d=clampi(t_dst[t],0,NTT-1);
        ssrc[t]=s; sdst[t]=d;
        atomicAdd(&sdeg[s],1); atomicAdd(&sdeg[NTT+d],1);
    }
    __syncthreads();
    if (t < NTT){
        onorm[t]=rsqrtf((float)max(sdeg[t],1));
        inorm[t]=rsqrtf((float)max(sdeg[NTT+t],1));
    }
    __syncthreads();

    // ----- layer 0 aggregation: h[d][k], k<48 (32 tfeats*onorm | 16 tef), double_act -----
    if (t < NTT*48){
        int d = t/48, k = t - d*48;
        float acc = 0.f;
        for (int e=0;e<ETT;e++){
            if (sdst[e]==d){
                int s = ssrc[e];
                float v = (k<TFF) ? tfeats[s*TFF+k]*onorm[s] : tef[e*TEE+(k-TFF)];
                acc += fmaxf(v,0.f);
            }
        }
        h[d][k] = acc;
    }
    __syncthreads();
    {   // GEMM0: K=48 split 12 per quarter
        float acc[NTT];
        #pragma unroll
        for (int n=0;n<NTT;n++) acc[n]=0.f;
        for (int i=0;i<12;i++){
            int k = q*12+i;
            float w = tW0[k*NHH+c];
            #pragma unroll
            for (int n=0;n<NTT;n++) acc[n]+=h[n][k]*w;
        }
        #pragma unroll
        for (int n=0;n<NTT;n++) part[q][n][c]=acc[n];
    }
    __syncthreads();
    {   // reduce + bias + relu
        float b = tb0[c];
        #pragma unroll
        for (int j=0;j<4;j++){
            int n = q*4+j;
            float v = part[0][n][c]+part[1][n][c]+part[2][n][c]+part[3][n][c];
            x[n][c] = fmaxf(v*inorm[n]+b,0.f);
        }
    }
    __syncthreads();

    // ----- layers 1..3 (tWr[0..2]), in = 256+16 -----
    for (int L=0;L<3;L++){
        const float* W = tWr + (size_t)L*(NHH+TEE)*NHH;
        // feat = feat * out_norm (each row scaled once; rows split by quarter)
        #pragma unroll
        for (int j=0;j<4;j++){
            int n = q*4+j;
            x[n][c] *= onorm[n];
        }
        __syncthreads();
        // h[d][k] edge aggregation (k<256: x rows, k>=256: tef)
        for (int ii=t; ii<NTT*(NHH+TEE); ii+=1024){
            int d = ii/(NHH+TEE), k = ii - d*(NHH+TEE);
            float acc=0.f;
            for (int e=0;e<ETT;e++){
                if (sdst[e]==d)
                    acc += (k<NHH) ? x[ssrc[e]][k] : tef[e*TEE+(k-NHH)];
            }
            h[d][k]=acc;
        }
        __syncthreads();
        // GEMM: K=272 split 68 per quarter
        float acc[NTT];
        #pragma unroll
        for (int n=0;n<NTT;n++) acc[n]=0.f;
        for (int i=0;i<68;i++){
            int k = q*68+i;
            float w = W[(size_t)k*NHH+c];
            #pragma unroll
            for (int n=0;n<NTT;n++) acc[n]+=h[n][k]*w;
        }
        #pragma unroll
        for (int n=0;n<NTT;n++) part[q][n][c]=acc[n];
        __syncthreads();
        float b = tbr[L*NHH+c];
        #pragma unroll
        for (int j=0;j<4;j++){
            int n = q*4+j;
            float v = part[0][n][c]+part[1][n][c]+part[2][n][c]+part[3][n][c];
            float val = v*inorm[n]+b;
            x[n][c] = (L<2) ? (x[n][c]+fmaxf(val,0.f)) : val;
        }
        __syncthreads();
    }
    // t_emb (group sums of 2) + relu (folds out of cGNN layer-0 double_act since out_norm>0)
    #pragma unroll
    for (int j=0;j<2;j++){
        int g = q*2+j;
        int i0=clampi(tgroups[g*2+0],0,NTT-1), i1=clampi(tgroups[g*2+1],0,NTT-1);
        g_relut[g*NHH+c]=fmaxf(x[i0][c]+x[i1][c],0.f);
    }
}

// v0[c] = sum_j relu_t[j] * cW0[68+j][c]  (collapsed broadcast GEMV, deterministic split)
__global__ __launch_bounds__(256) void k_v0(const float* __restrict__ cW0){
    int b=blockIdx.x, c=threadIdx.x;
    const float* Wm = cW0 + (size_t)(CFF+OPEE + b*NHH)*NHH;
    const float* rt = g_relut + b*NHH;
    float acc=0.f;
    for (int j=0;j<NHH;j++) acc += rt[j]*Wm[(size_t)j*NHH+c];
    g_v0p[b*NHH+c]=acc;
}
__global__ __launch_bounds__(256) void k_v0r(){
    int c=threadIdx.x;
    float s=0.f;
    for (int b=0;b<TGG;b++) s+=g_v0p[b*NHH+c];
    g_v0[c]=s;
}

// ---------------- cGNN layer 0 (fused gather + GEMM) ----------------
// feat row layout of cW0: [0:64] cfeats | [64:68] opemb | [68:2116] t_flat | [2116:2132] cedge
__global__ __launch_bounds__(256) void k_l0(
    const int* __restrict__ ctypes,
    const float* __restrict__ cfeats, const float* __restrict__ opemb,
    const float* __restrict__ cW0, const float* __restrict__ cb0)
{
    __shared__ float sh[NPB][72];    // [node][k: 0..63 cfeats, 64..67 opemb, 68 s_on]
    __shared__ float se[NPB][CEE];
    int d0=blockIdx.x*NPB, t=threadIdx.x;
    if (t < NPB*CEE){ int n=t/CEE,k=t%CEE; se[n][k]=g_eaggR[(size_t)(d0+n)*CEE+k]; }
    int g=t/72, k=t%72;
    if (g<3){
        for (int n=g;n<NPB;n+=3){
            int d=d0+n;
            int b=clampi(g_off[d],0,ECN), e=clampi(g_off[d+1],b,ECN);
            float acc=0.f;
            for (int i=b;i<e;i++){
                int s=g_srcarr[i];
                float on=g_onorm[s];
                float v;
                if (k<CFF)            v=fmaxf(cfeats[(size_t)s*CFF+k],0.f);
                else if (k<CFF+OPEE)  v=fmaxf(opemb[clampi(ctypes[s],0,255)*OPEE+(k-CFF)],0.f);
                else                  v=(k==68)?1.f:0.f;
                acc += v*on;
            }
            sh[n][k]=acc;
        }
    }
    __syncthreads();
    float acc[NPB];
    #pragma unroll
    for (int n=0;n<NPB;n++) acc[n]=0.f;
    for (int kk=0;kk<CFF+OPEE;kk++){
        float w=cW0[(size_t)kk*NHH+t];
        #pragma unroll
        for (int n=0;n<NPB;n++) acc[n]+=sh[n][kk]*w;
    }
    {
        float w=g_v0[t];
        #pragma unroll
        for (int n=0;n<NPB;n++) acc[n]+=sh[n][68]*w;   // s_on * v0 (collapsed t_flat block)
    }
    const float* We = cW0 + (size_t)(CFF+OPEE+TGG*NHH)*NHH;
    #pragma unroll
    for (int kk=0;kk<CEE;kk++){
        float w=We[(size_t)kk*NHH+t];
        #pragma unroll
        for (int n=0;n<NPB;n++) acc[n]+=se[n][kk]*w;
    }
    float bb=cb0[t];
    #pragma unroll
    for (int n=0;n<NPB;n++){
        int d=d0+n;
        g_x0[(size_t)d*NHH+t]=fmaxf(acc[n]*g_inorm[d]+bb,0.f);
    }
}

// ---------------- recurrent layers (wave-split-K, 4 cols/lane, ping-pong via template) ----------------
template<int DIR>   // DIR=0: x0->x1, DIR=1: x1->x0
__global__ __launch_bounds__(256) void k_layer(
    const float* __restrict__ W, const float* __restrict__ bias, int relu_res)
{
    const float* xin  = DIR ? g_x1 : g_x0;
    float*       xout = DIR ? g_x0 : g_x1;
    __shared__ float sh[NPB][NHH+CEE];       // 8.7 KB: gathered features + eagg
    __shared__ float part[4][NPB][NHH];      // 32 KB: per-wave K-partials
    const int d0 = blockIdx.x*NPB;
    const int t = threadIdx.x, lane = t & 63, q = t >> 6;

    // gather: wave q fills nodes 2q, 2q+1 (lane owns cols lane+{0,64,128,192})
    #pragma unroll
    for (int nn=0; nn<2; ++nn){
        int n = 2*q+nn, d = d0+n;
        int b = clampi(g_off[d],0,ECN), e = clampi(g_off[d+1],b,ECN);
        float a0=0.f,a1=0.f,a2=0.f,a3=0.f;
        for (int i=b;i<e;i++){
            int s = g_srcarr[i];
            float on = g_onorm[s];
            const float* xr = xin + (size_t)s*NHH + lane;
            a0 += xr[0]*on; a1 += xr[64]*on; a2 += xr[128]*on; a3 += xr[192]*on;
        }
        sh[n][lane]=a0; sh[n][lane+64]=a1; sh[n][lane+128]=a2; sh[n][lane+192]=a3;
    }
    if (t < NPB*CEE){ int n=t>>4, f=t&15; sh[n][NHH+f]=g_eagg[(size_t)(d0+n)*CEE+f]; }
    __syncthreads();

    // GEMM: wave q covers k in [68q, 68q+68); lane computes 4 cols x 8 nodes
    float acc[4][NPB];
    #pragma unroll
    for (int j=0;j<4;j++)
        #pragma unroll
        for (int n=0;n<NPB;n++) acc[j][n]=0.f;
    const int k0 = q*68;
    for (int i=0;i<68;i++){
        int k = k0+i;
        const float* wr = W + (size_t)k*NHH + lane;
        float w0=wr[0], w1=wr[64], w2=wr[128], w3=wr[192];
        #pragma unroll
        for (int n=0;n<NPB;n++){
            float hv = sh[n][k];
            acc[0][n]+=hv*w0; acc[1][n]+=hv*w1; acc[2][n]+=hv*w2; acc[3][n]+=hv*w3;
        }
    }
    #pragma unroll
    for (int n=0;n<NPB;n++){
        part[q][n][lane]     = acc[0][n];
        part[q][n][lane+64]  = acc[1][n];
        part[q][n][lane+128] = acc[2][n];
        part[q][n][lane+192] = acc[3][n];
    }
    __syncthreads();

    // reduce + epilogue: thread t owns col t for all 8 nodes
    float bb = bias[t];
    #pragma unroll
    for (int n=0;n<NPB;n++){
        int d = d0+n;
        float v = part[0][n][t]+part[1][n][t]+part[2][n][t]+part[3][n][t];
        float val = v*g_inorm[d]+bb;
        float y = relu_res ? (xin[(size_t)d*NHH+t]*g_onorm[d] + fmaxf(val,0.f)) : val;
        xout[(size_t)d*NHH+t]=y;
    }
}

// ---------------- pooling + heads ----------------
__global__ __launch_bounds__(256) void k_cemb(const int* __restrict__ cgroups){
    int g=blockIdx.x, c=threadIdx.x;
    float s=0.f;
    for (int i=0;i<GSZ;i++){
        int idx=clampi(cgroups[g*GSZ+i],0,NCN-1);
        s += g_x1[(size_t)idx*NHH+c];
    }
    g_cemb[g*NHH+c]=s;
}

__global__ __launch_bounds__(256) void k_heads(
    const float* __restrict__ sW, const float* __restrict__ sb,
    const float* __restrict__ nW, const float* __restrict__ nb, float* __restrict__ out)
{
    __shared__ float red[256];
    __shared__ float z[9];
    int g=blockIdx.x, t=threadIdx.x;
    float e = g_cemb[(size_t)g*NHH+t];
    for (int j=0;j<9;j++){
        float w = (j==0) ? nW[t] : sW[t*TGG+(j-1)];
        red[t]=e*w; __syncthreads();
        for (int s=128;s>0;s>>=1){ if (t<s) red[t]+=red[t+s]; __syncthreads(); }
        if (t==0) z[j]=red[0];
        __syncthreads();
    }
    if (t==0){
        float z0 = z[0] + nb[0];
        float lsig = fminf(z0,0.f) - log1pf(expf(-fabsf(z0)));
        out[g*9+0]=lsig;
        float zz[8]; float m=-1e30f;
        for (int j=0;j<8;j++){ zz[j]=z[j+1]+sb[j]; m=fmaxf(m,zz[j]); }
        float s=0.f;
        for (int j=0;j<8;j++) s+=expf(zz[j]-m);
        float lse=m+logf(s);
        for (int j=0;j<8;j++) out[g*9+1+j]=zz[j]-lse;
    }
}

extern "C" void kernel_launch(void* const* d_in, const int* in_sizes, int n_in,
                              void* d_out, int out_size, void* d_ws, size_t ws_size,
                              hipStream_t stream) {
    const int expect[24] = {
        NCN*CFF, ECN*CEE, NTT*TFF, ETT*TEE, 256*OPEE,
        (TFF+TEE)*NHH, NHH, 3*(NHH+TEE)*NHH, 3*NHH,
        (CFF+OPEE+TGG*NHH+CEE)*NHH, NHH, 5*(NHH+CEE)*NHH, 5*NHH,
        NHH*TGG, TGG, NHH, 1,
        NCN, ECN, ECN, ETT, ETT, GCN*GSZ, TGG*2
    };
    if (n_in < 24){
        k_badsize<<<(out_size+255)/256,256,0,stream>>>((float*)d_out, out_size, 2.0e6f);
        return;
    }
    for (int i=0;i<24;i++){
        if (in_sizes[i] != expect[i]){
            k_badsize<<<(out_size+255)/256,256,0,stream>>>((float*)d_out, out_size, 1.0e6f+(float)i);
            return;
        }
    }

    const float* cfeats = (const float*)d_in[0];
    const float* cef    = (const float*)d_in[1];
    const float* tfeats = (const float*)d_in[2];
    const float* tef    = (const float*)d_in[3];
    const float* opemb  = (const float*)d_in[4];
    const float* tW0    = (const float*)d_in[5];
    const float* tb0    = (const float*)d_in[6];
    const float* tWr    = (const float*)d_in[7];
    const float* tbr    = (const float*)d_in[8];
    const float* cW0    = (const float*)d_in[9];
    const float* cb0    = (const float*)d_in[10];
    const float* cWr    = (const float*)d_in[11];
    const float* cbr    = (const float*)d_in[12];
    const float* sW     = (const float*)d_in[13];
    const float* sb     = (const float*)d_in[14];
    const float* nW     = (const float*)d_in[15];
    const float* nb     = (const float*)d_in[16];
    const int* ctypes   = (const int*)d_in[17];
    const int* c_src    = (const int*)d_in[18];
    const int* c_dst    = (const int*)d_in[19];
    const int* t_src    = (const int*)d_in[20];
    const int* t_dst    = (const int*)d_in[21];
    const int* cgroups  = (const int*)d_in[22];
    const int* tgroups  = (const int*)d_in[23];

    const int EB = (ECN+255)/256, NB = (NCN+255)/256;

    k_zero3   <<<NB, 256, 0, stream>>>();
    k_degrees <<<EB, 256, 0, stream>>>(c_src, c_dst);
    k_norms   <<<NB, 256, 0, stream>>>();
    k_scan    <<<1, 1024, 0, stream>>>();
    k_scatter <<<EB, 256, 0, stream>>>(c_dst);
    k_sortfill<<<NB, 256, 0, stream>>>(c_src);
    k_eagg    <<<(NCN+15)/16, 256, 0, stream>>>(cef);

    k_topo    <<<1, 1024, 0, stream>>>(tfeats, tef, tW0, tb0, tWr, tbr, t_src, t_dst, tgroups);
    k_v0      <<<TGG, 256, 0, stream>>>(cW0);
    k_v0r     <<<1, 256, 0, stream>>>();

    k_l0      <<<NCN/NPB, 256, 0, stream>>>(ctypes, cfeats, opemb, cW0, cb0);

    // 5 recurrent layers: x0 -> x1 -> x0 -> x1 -> x0 -> x1  (final in g_x1)
    k_layer<0><<<NCN/NPB, 256, 0, stream>>>(cWr + (size_t)0*(NHH+CEE)*NHH, cbr + 0*NHH, 1);
    k_layer<1><<<NCN/NPB, 256, 0, stream>>>(cWr + (size_t)1*(NHH+CEE)*NHH, cbr + 1*NHH, 1);
    k_layer<0><<<NCN/NPB, 256, 0, stream>>>(cWr + (size_t)2*(NHH+CEE)*NHH, cbr + 2*NHH, 1);
    k_layer<1><<<NCN/NPB, 256, 0, stream>>>(cWr + (size_t)3*(NHH+CEE)*NHH, cbr + 3*NHH, 1);
    k_layer<0><<<NCN/NPB, 256, 0, stream>>>(cWr + (size_t)4*(NHH+CEE)*NHH, cbr + 4*NHH, 0);

    k_cemb <<<GCN, 256, 0, stream>>>(cgroups);
    k_heads<<<GCN, 256, 0, stream>>>(sW, sb, nW, nb, (float*)d_out);
}

// Round 6
// 528.680 us; speedup vs baseline: 1.7165x; 1.0600x over previous
//
#include <hip/hip_runtime.h>
#include <hip/hip_bf16.h>

#define NCN 10000   // computation nodes
#define ECN 120000  // computation edges
#define NHH 256     // hidden
#define CEE 16      // cedge feat dim  (CF,CE = 64,16)
#define GCN 100     // cgroups
#define GSZ 100     // nodes per cgroup
#define NTT 16      // topo nodes
#define ETT 64      // topo edges
#define TGG 8       // tgroups
#define OPEE 4
#define CFF 64
#define TFF 32
#define TEE 16
#define NPB 8       // dst nodes per block in fused layer kernels

// ---------- static device scratch (no d_ws dependency) ----------
__device__ int   g_indeg[NCN];
__device__ int   g_outdeg[NCN];
__device__ int   g_cursor[NCN];
__device__ int   g_off[NCN+1];
__device__ int   g_eid[ECN];
__device__ int   g_srcarr[ECN];
__device__ float g_onorm[NCN];
__device__ float g_inorm[NCN];
__device__ float g_eagg [NCN*CEE];
__device__ float g_eaggR[NCN*CEE];
__device__ float g_tx0[NTT*NHH];
__device__ float g_tx1[NTT*NHH];
__device__ float g_v0p[TGG*NHH];
__device__ float g_v0[NHH];
__device__ float g_x0[(size_t)NCN*NHH];
__device__ float g_x1[(size_t)NCN*NHH];
__device__ float g_cemb[GCN*NHH];

__device__ __forceinline__ int clampi(int v,int lo,int hi){ return v<lo?lo:(v>hi?hi:v); }

// diagnostic: on input-size mismatch write 1e6+idx so absmax reveals the index
__global__ __launch_bounds__(256) void k_badsize(float* out, int n, float code){
    int i = blockIdx.x*256 + threadIdx.x;
    if (i < n) out[i] = code;
}

// ---------------- graph prep ----------------
__global__ __launch_bounds__(256) void k_zero3(){
    int i = blockIdx.x*256 + threadIdx.x;
    if (i < NCN){ g_indeg[i]=0; g_outdeg[i]=0; g_cursor[i]=0; }
}

__global__ __launch_bounds__(256) void k_degrees(const int* __restrict__ src, const int* __restrict__ dst){
    int e = blockIdx.x*256 + threadIdx.x;
    if (e < ECN){
        atomicAdd(&g_outdeg[clampi(src[e],0,NCN-1)],1);
        atomicAdd(&g_indeg [clampi(dst[e],0,NCN-1)],1);
    }
}

__global__ __launch_bounds__(256) void k_norms(){
    int i = blockIdx.x*256 + threadIdx.x;
    if (i < NCN){
        g_onorm[i] = rsqrtf((float)max(g_outdeg[i],1));
        g_inorm[i] = rsqrtf((float)max(g_indeg[i],1));
    }
}

// exclusive scan of indeg -> off[0..NCN]
__global__ __launch_bounds__(1024) void k_scan(){
    __shared__ int cs[1024];
    const int CH = (NCN + 1023)/1024;  // 10
    int t = threadIdx.x;
    int base = t*CH;
    int s = 0;
    for (int j=0;j<CH;j++){ int idx=base+j; if (idx<NCN) s += g_indeg[idx]; }
    cs[t] = s; __syncthreads();
    for (int ofs=1; ofs<1024; ofs<<=1){
        int v = (t>=ofs) ? cs[t-ofs] : 0;
        __syncthreads();
        cs[t] += v;
        __syncthreads();
    }
    int run = (t==0) ? 0 : cs[t-1];
    for (int j=0;j<CH;j++){
        int idx = base+j;
        if (idx <= NCN) g_off[idx] = run;
        if (idx < NCN) run += g_indeg[idx];
    }
}

__global__ __launch_bounds__(256) void k_scatter(const int* __restrict__ dst){
    int e = blockIdx.x*256 + threadIdx.x;
    if (e < ECN){
        int d = clampi(dst[e],0,NCN-1);
        int pos = g_off[d] + atomicAdd(&g_cursor[d],1);
        g_eid[clampi(pos,0,ECN-1)] = e;
    }
}

// per-node insertion sort by eid (deterministic edge order) + fill src ids
__global__ __launch_bounds__(256) void k_sortfill(const int* __restrict__ c_src){
    int d = blockIdx.x*256 + threadIdx.x;
    if (d < NCN){
        int b = clampi(g_off[d],0,ECN), e = clampi(g_off[d+1],b,ECN);
        for (int i=b+1;i<e;i++){
            int key = g_eid[i]; int j = i-1;
            while (j>=b && g_eid[j]>key){ g_eid[j+1]=g_eid[j]; j--; }
            g_eid[j+1] = key;
        }
        for (int i=b;i<e;i++) g_srcarr[i] = clampi(c_src[clampi(g_eid[i],0,ECN-1)],0,NCN-1);
    }
}

// eagg[d][f] = sum efeat, eaggR[d][f] = sum relu(efeat)  (layer-invariant)
__global__ __launch_bounds__(256) void k_eagg(const float* __restrict__ ef){
    int d = blockIdx.x*16 + threadIdx.x/16;
    int f = threadIdx.x%16;
    if (d < NCN){
        float s=0.f, sr=0.f;
        int b=clampi(g_off[d],0,ECN), e=clampi(g_off[d+1],b,ECN);
        for (int i=b;i<e;i++){
            float v = ef[(size_t)clampi(g_eid[i],0,ECN-1)*CEE + f];
            s += v; sr += fmaxf(v,0.f);
        }
        g_eagg [(size_t)d*CEE+f] = s;
        g_eaggR[(size_t)d*CEE+f] = sr;
    }
}

// ---- topo helpers: per-block edge cache + degree norms (cheap, avoids prep kernel) ----
__device__ __forceinline__ void topo_edges_norms(
    const int* __restrict__ t_src, const int* __restrict__ t_dst,
    int* ssrc, int* sdst, int* sdeg, float* onrm, float* inrm, int t)
{
    if (t < 2*NTT) sdeg[t]=0;
    __syncthreads();
    if (t < ETT){
        int s=clampi(t_src[t],0,NTT-1), d=clampi(t_dst[t],0,NTT-1);
        ssrc[t]=s; sdst[t]=d;
        atomicAdd(&sdeg[s],1); atomicAdd(&sdeg[NTT+d],1);
    }
    __syncthreads();
    if (t < NTT){
        onrm[t]=rsqrtf((float)max(sdeg[t],1));
        inrm[t]=rsqrtf((float)max(sdeg[NTT+t],1));
    }
    __syncthreads();
}

// ---------------- topo layer 0 (16 blocks, one per dst node) ----------------
__global__ __launch_bounds__(256) void kt_l0(
    const float* __restrict__ tfeats, const float* __restrict__ tef,
    const float* __restrict__ tW0, const float* __restrict__ tb0,
    const int* __restrict__ t_src, const int* __restrict__ t_dst)
{
    __shared__ float h[48];
    __shared__ int ssrc[ETT], sdst[ETT], sdeg[2*NTT];
    __shared__ float onrm[NTT], inrm[NTT];
    const int d = blockIdx.x, t = threadIdx.x;
    topo_edges_norms(t_src, t_dst, ssrc, sdst, sdeg, onrm, inrm, t);
    if (t < 48){
        float acc=0.f;
        for (int e=0;e<ETT;e++){
            if (sdst[e]==d){
                int s=ssrc[e];
                float v = (t<TFF) ? tfeats[s*TFF+t]*onrm[s] : tef[e*TEE+(t-TFF)];
                acc += fmaxf(v,0.f);
            }
        }
        h[t]=acc;
    }
    __syncthreads();
    float acc=0.f;
    for (int k=0;k<48;k++) acc += h[k]*tW0[k*NHH+t];
    g_tx0[d*NHH+t] = fmaxf(acc*inrm[d]+tb0[t], 0.f);
}

// ---------------- topo recurrent layer (16 blocks) ----------------
template<int DIR>  // DIR=0: tx0->tx1, DIR=1: tx1->tx0
__global__ __launch_bounds__(256) void kt_lr(
    const float* __restrict__ tef,
    const float* __restrict__ W, const float* __restrict__ bias,
    const int* __restrict__ t_src, const int* __restrict__ t_dst, int relu_res)
{
    const float* xin  = DIR ? g_tx1 : g_tx0;
    float*       xout = DIR ? g_tx0 : g_tx1;
    __shared__ float h[NHH+TEE];
    __shared__ int ssrc[ETT], sdst[ETT], sdeg[2*NTT];
    __shared__ float onrm[NTT], inrm[NTT];
    const int d = blockIdx.x, t = threadIdx.x;
    topo_edges_norms(t_src, t_dst, ssrc, sdst, sdeg, onrm, inrm, t);
    {   // h[t] (hidden part) and h[256+t] for t<16 (edge-feat part)
        float a0=0.f, a1=0.f;
        for (int e=0;e<ETT;e++){
            if (sdst[e]==d){
                a0 += xin[ssrc[e]*NHH+t]*onrm[ssrc[e]];
                if (t<TEE) a1 += tef[e*TEE+t];
            }
        }
        h[t]=a0;
        if (t<TEE) h[NHH+t]=a1;
    }
    __syncthreads();
    float acc=0.f;
    for (int k=0;k<NHH+TEE;k++) acc += h[k]*W[(size_t)k*NHH+t];
    float val = acc*inrm[d] + bias[t];
    xout[d*NHH+t] = relu_res ? (xin[d*NHH+t]*onrm[d] + fmaxf(val,0.f)) : val;
}

// v0 partial: block b computes relut row b (group sum + relu) in LDS, then GEMV slice
__global__ __launch_bounds__(256) void k_v0(const float* __restrict__ cW0, const int* __restrict__ tgroups){
    __shared__ float srt[NHH];
    int b=blockIdx.x, c=threadIdx.x;
    int i0=clampi(tgroups[b*2+0],0,NTT-1), i1=clampi(tgroups[b*2+1],0,NTT-1);
    srt[c]=fmaxf(g_tx1[i0*NHH+c]+g_tx1[i1*NHH+c],0.f);
    __syncthreads();
    const float* Wm = cW0 + (size_t)(CFF+OPEE + b*NHH)*NHH;
    float acc=0.f;
    for (int j=0;j<NHH;j++) acc += srt[j]*Wm[(size_t)j*NHH+c];
    g_v0p[b*NHH+c]=acc;
}
__global__ __launch_bounds__(256) void k_v0r(){
    int c=threadIdx.x;
    float s=0.f;
    for (int b=0;b<TGG;b++) s+=g_v0p[b*NHH+c];
    g_v0[c]=s;
}

// ---------------- cGNN layer 0 (fused gather + GEMM) ----------------
// feat row layout of cW0: [0:64] cfeats | [64:68] opemb | [68:2116] t_flat | [2116:2132] cedge
__global__ __launch_bounds__(256) void k_l0(
    const int* __restrict__ ctypes,
    const float* __restrict__ cfeats, const float* __restrict__ opemb,
    const float* __restrict__ cW0, const float* __restrict__ cb0)
{
    __shared__ float sh[NPB][72];    // [node][k: 0..63 cfeats, 64..67 opemb, 68 s_on]
    __shared__ float se[NPB][CEE];
    int d0=blockIdx.x*NPB, t=threadIdx.x;
    if (t < NPB*CEE){ int n=t/CEE,k=t%CEE; se[n][k]=g_eaggR[(size_t)(d0+n)*CEE+k]; }
    int g=t/72, k=t%72;
    if (g<3){
        for (int n=g;n<NPB;n+=3){
            int d=d0+n;
            int b=clampi(g_off[d],0,ECN), e=clampi(g_off[d+1],b,ECN);
            float acc=0.f;
            for (int i=b;i<e;i++){
                int s=g_srcarr[i];
                float on=g_onorm[s];
                float v;
                if (k<CFF)            v=fmaxf(cfeats[(size_t)s*CFF+k],0.f);
                else if (k<CFF+OPEE)  v=fmaxf(opemb[clampi(ctypes[s],0,255)*OPEE+(k-CFF)],0.f);
                else                  v=(k==68)?1.f:0.f;
                acc += v*on;
            }
            sh[n][k]=acc;
        }
    }
    __syncthreads();
    float acc[NPB];
    #pragma unroll
    for (int n=0;n<NPB;n++) acc[n]=0.f;
    for (int kk=0;kk<CFF+OPEE;kk++){
        float w=cW0[(size_t)kk*NHH+t];
        #pragma unroll
        for (int n=0;n<NPB;n++) acc[n]+=sh[n][kk]*w;
    }
    {
        float w=g_v0[t];
        #pragma unroll
        for (int n=0;n<NPB;n++) acc[n]+=sh[n][68]*w;   // s_on * v0 (collapsed t_flat block)
    }
    const float* We = cW0 + (size_t)(CFF+OPEE+TGG*NHH)*NHH;
    #pragma unroll
    for (int kk=0;kk<CEE;kk++){
        float w=We[(size_t)kk*NHH+t];
        #pragma unroll
        for (int n=0;n<NPB;n++) acc[n]+=se[n][kk]*w;
    }
    float bb=cb0[t];
    #pragma unroll
    for (int n=0;n<NPB;n++){
        int d=d0+n;
        g_x0[(size_t)d*NHH+t]=fmaxf(acc[n]*g_inorm[d]+bb,0.f);
    }
}

// ------- recurrent layers: wave-split-K GEMM in two column-halves (25.6 KB LDS) -------
template<int DIR>   // DIR=0: x0->x1, DIR=1: x1->x0
__global__ __launch_bounds__(256) void k_layer(
    const float* __restrict__ W, const float* __restrict__ bias, int relu_res)
{
    const float* xin  = DIR ? g_x1 : g_x0;
    float*       xout = DIR ? g_x0 : g_x1;
    __shared__ float sh[NPB][NHH+CEE];       // 9 KB: gathered features + eagg
    __shared__ float part[4][NPB][128];      // 16 KB: per-wave K-partials (half the cols)
    const int d0 = blockIdx.x*NPB;
    const int t = threadIdx.x, lane = t & 63, q = t >> 6;

    // gather: wave q fills nodes 2q, 2q+1 (lane owns cols lane+{0,64,128,192})
    #pragma unroll
    for (int nn=0; nn<2; ++nn){
        int n = 2*q+nn, d = d0+n;
        int b = clampi(g_off[d],0,ECN), e = clampi(g_off[d+1],b,ECN);
        float a0=0.f,a1=0.f,a2=0.f,a3=0.f;
        for (int i=b;i<e;i++){
            int s = g_srcarr[i];
            float on = g_onorm[s];
            const float* xr = xin + (size_t)s*NHH + lane;
            a0 += xr[0]*on; a1 += xr[64]*on; a2 += xr[128]*on; a3 += xr[192]*on;
        }
        sh[n][lane]=a0; sh[n][lane+64]=a1; sh[n][lane+128]=a2; sh[n][lane+192]=a3;
    }
    if (t < NPB*CEE){ int n=t>>4, f=t&15; sh[n][NHH+f]=g_eagg[(size_t)(d0+n)*CEE+f]; }
    __syncthreads();

    const int k0 = q*68;
    #pragma unroll
    for (int half=0; half<2; ++half){
        // GEMM: wave q covers k in [68q,68q+68); lane computes 2 cols (of this half) x 8 nodes
        float a0[NPB], a1[NPB];
        #pragma unroll
        for (int n=0;n<NPB;n++){ a0[n]=0.f; a1[n]=0.f; }
        for (int i=0;i<68;i++){
            int k = k0+i;
            const float* wr = W + (size_t)k*NHH + half*128 + lane;
            float w0=wr[0], w1=wr[64];
            #pragma unroll
            for (int n=0;n<NPB;n++){
                float hv = sh[n][k];
                a0[n]+=hv*w0; a1[n]+=hv*w1;
            }
        }
        #pragma unroll
        for (int n=0;n<NPB;n++){
            part[q][n][lane]    = a0[n];
            part[q][n][lane+64] = a1[n];
        }
        __syncthreads();
        // reduce + epilogue for this half: 1024 entries over 256 threads
        #pragma unroll
        for (int j=0;j<4;j++){
            int idx = j*256+t;
            int n = idx>>7, c = idx&127, col = half*128+c;
            int d = d0+n;
            float v = part[0][n][c]+part[1][n][c]+part[2][n][c]+part[3][n][c];
            float val = v*g_inorm[d]+bias[col];
            float y = relu_res ? (xin[(size_t)d*NHH+col]*g_onorm[d] + fmaxf(val,0.f)) : val;
            xout[(size_t)d*NHH+col]=y;
        }
        __syncthreads();
    }
}

// ---------------- pooling + heads ----------------
__global__ __launch_bounds__(256) void k_cemb(const int* __restrict__ cgroups){
    int g=blockIdx.x, c=threadIdx.x;
    float s=0.f;
    for (int i=0;i<GSZ;i++){
        int idx=clampi(cgroups[g*GSZ+i],0,NCN-1);
        s += g_x1[(size_t)idx*NHH+c];
    }
    g_cemb[g*NHH+c]=s;
}

__global__ __launch_bounds__(256) void k_heads(
    const float* __restrict__ sW, const float* __restrict__ sb,
    const float* __restrict__ nW, const float* __restrict__ nb, float* __restrict__ out)
{
    __shared__ float red[256];
    __shared__ float z[9];
    int g=blockIdx.x, t=threadIdx.x;
    float e = g_cemb[(size_t)g*NHH+t];
    for (int j=0;j<9;j++){
        float w = (j==0) ? nW[t] : sW[t*TGG+(j-1)];
        red[t]=e*w; __syncthreads();
        for (int s=128;s>0;s>>=1){ if (t<s) red[t]+=red[t+s]; __syncthreads(); }
        if (t==0) z[j]=red[0];
        __syncthreads();
    }
    if (t==0){
        float z0 = z[0] + nb[0];
        float lsig = fminf(z0,0.f) - log1pf(expf(-fabsf(z0)));
        out[g*9+0]=lsig;
        float zz[8]; float m=-1e30f;
        for (int j=0;j<8;j++){ zz[j]=z[j+1]+sb[j]; m=fmaxf(m,zz[j]); }
        float s=0.f;
        for (int j=0;j<8;j++) s+=expf(zz[j]-m);
        float lse=m+logf(s);
        for (int j=0;j<8;j++) out[g*9+1+j]=zz[j]-lse;
    }
}

extern "C" void kernel_launch(void* const* d_in, const int* in_sizes, int n_in,
                              void* d_out, int out_size, void* d_ws, size_t ws_size,
                              hipStream_t stream) {
    const int expect[24] = {
        NCN*CFF, ECN*CEE, NTT*TFF, ETT*TEE, 256*OPEE,
        (TFF+TEE)*NHH, NHH, 3*(NHH+TEE)*NHH, 3*NHH,
        (CFF+OPEE+TGG*NHH+CEE)*NHH, NHH, 5*(NHH+CEE)*NHH, 5*NHH,
        NHH*TGG, TGG, NHH, 1,
        NCN, ECN, ECN, ETT, ETT, GCN*GSZ, TGG*2
    };
    if (n_in < 24){
        k_badsize<<<(out_size+255)/256,256,0,stream>>>((float*)d_out, out_size, 2.0e6f);
        return;
    }
    for (int i=0;i<24;i++){
        if (in_sizes[i] != expect[i]){
            k_badsize<<<(out_size+255)/256,256,0,stream>>>((float*)d_out, out_size, 1.0e6f+(float)i);
            return;
        }
    }

    const float* cfeats = (const float*)d_in[0];
    const float* cef    = (const float*)d_in[1];
    const float* tfeats = (const float*)d_in[2];
    const float* tef    = (const float*)d_in[3];
    const float* opemb  = (const float*)d_in[4];
    const float* tW0    = (const float*)d_in[5];
    const float* tb0    = (const float*)d_in[6];
    const float* tWr    = (const float*)d_in[7];
    const float* tbr    = (const float*)d_in[8];
    const float* cW0    = (const float*)d_in[9];
    const float* cb0    = (const float*)d_in[10];
    const float* cWr    = (const float*)d_in[11];
    const float* cbr    = (const float*)d_in[12];
    const float* sW     = (const float*)d_in[13];
    const float* sb     = (const float*)d_in[14];
    const float* nW     = (const float*)d_in[15];
    const float* nb     = (const float*)d_in[16];
    const int* ctypes   = (const int*)d_in[17];
    const int* c_src    = (const int*)d_in[18];
    const int* c_dst    = (const int*)d_in[19];
    const int* t_src    = (const int*)d_in[20];
    const int* t_dst    = (const int*)d_in[21];
    const int* cgroups  = (const int*)d_in[22];
    const int* tgroups  = (const int*)d_in[23];

    const int EB = (ECN+255)/256, NB = (NCN+255)/256;

    k_zero3   <<<NB, 256, 0, stream>>>();
    k_degrees <<<EB, 256, 0, stream>>>(c_src, c_dst);
    k_norms   <<<NB, 256, 0, stream>>>();
    k_scan    <<<1, 1024, 0, stream>>>();
    k_scatter <<<EB, 256, 0, stream>>>(c_dst);
    k_sortfill<<<NB, 256, 0, stream>>>(c_src);
    k_eagg    <<<(NCN+15)/16, 256, 0, stream>>>(cef);

    // topo GNN: 16-block per-layer kernels, ping-pong tx0/tx1 (final in tx1)
    kt_l0    <<<NTT, 256, 0, stream>>>(tfeats, tef, tW0, tb0, t_src, t_dst);
    kt_lr<0> <<<NTT, 256, 0, stream>>>(tef, tWr + (size_t)0*(NHH+TEE)*NHH, tbr + 0*NHH, t_src, t_dst, 1);
    kt_lr<1> <<<NTT, 256, 0, stream>>>(tef, tWr + (size_t)1*(NHH+TEE)*NHH, tbr + 1*NHH, t_src, t_dst, 1);
    kt_lr<0> <<<NTT, 256, 0, stream>>>(tef, tWr + (size_t)2*(NHH+TEE)*NHH, tbr + 2*NHH, t_src, t_dst, 0);
    k_v0     <<<TGG, 256, 0, stream>>>(cW0, tgroups);
    k_v0r    <<<1, 256, 0, stream>>>();

    k_l0     <<<NCN/NPB, 256, 0, stream>>>(ctypes, cfeats, opemb, cW0, cb0);

    // 5 recurrent layers: x0 -> x1 -> x0 -> x1 -> x0 -> x1  (final in g_x1)
    k_layer<0><<<NCN/NPB, 256, 0, stream>>>(cWr + (size_t)0*(NHH+CEE)*NHH, cbr + 0*NHH, 1);
    k_layer<1><<<NCN/NPB, 256, 0, stream>>>(cWr + (size_t)1*(NHH+CEE)*NHH, cbr + 1*NHH, 1);
    k_layer<0><<<NCN/NPB, 256, 0, stream>>>(cWr + (size_t)2*(NHH+CEE)*NHH, cbr + 2*NHH, 1);
    k_layer<1><<<NCN/NPB, 256, 0, stream>>>(cWr + (size_t)3*(NHH+CEE)*NHH, cbr + 3*NHH, 1);
    k_layer<0><<<NCN/NPB, 256, 0, stream>>>(cWr + (size_t)4*(NHH+CEE)*NHH, cbr + 4*NHH, 0);

    k_cemb <<<GCN, 256, 0, stream>>>(cgroups);
    k_heads<<<GCN, 256, 0, stream>>>(sW, sb, nW, nb, (float*)d_out);
}

// Round 7
// 520.256 us; speedup vs baseline: 1.7443x; 1.0162x over previous
//
#include <hip/hip_runtime.h>
#include <hip/hip_bf16.h>

#define NCN 10000   // computation nodes
#define ECN 120000  // computation edges
#define NHH 256     // hidden
#define CEE 16      // cedge feat dim  (CF,CE = 64,16)
#define GCN 100     // cgroups
#define GSZ 100     // nodes per cgroup
#define NTT 16      // topo nodes
#define ETT 64      // topo edges
#define TGG 8       // tgroups
#define OPEE 4
#define CFF 64
#define TFF 32
#define TEE 16
#define NPB 8       // dst nodes per block in fused layer kernels

// ---------- static device scratch (no d_ws dependency) ----------
__device__ int   g_indeg[NCN];
__device__ int   g_outdeg[NCN];
__device__ int   g_cursor[NCN];
__device__ int   g_off[NCN+1];
__device__ int   g_eid[ECN];
__device__ int   g_srcarr[ECN];
__device__ float g_onorm[NCN];
__device__ float g_inorm[NCN];
__device__ float g_eagg [NCN*CEE];
__device__ float g_eaggR[NCN*CEE];
__device__ float g_tx0[NTT*NHH];
__device__ float g_tx1[NTT*NHH];
__device__ float g_v0p[TGG*NHH];
__device__ float g_v0[NHH];
__device__ float g_x0[(size_t)NCN*NHH];
__device__ float g_x1[(size_t)NCN*NHH];
__device__ float g_cembp[4*GCN*NHH];

__device__ __forceinline__ int clampi(int v,int lo,int hi){ return v<lo?lo:(v>hi?hi:v); }

// diagnostic: on input-size mismatch write 1e6+idx so absmax reveals the index
__global__ __launch_bounds__(256) void k_badsize(float* out, int n, float code){
    int i = blockIdx.x*256 + threadIdx.x;
    if (i < n) out[i] = code;
}

// ---------------- graph prep ----------------
__global__ __launch_bounds__(256) void k_zero3(){
    int i = blockIdx.x*256 + threadIdx.x;
    if (i < NCN){ g_indeg[i]=0; g_outdeg[i]=0; g_cursor[i]=0; }
}

__global__ __launch_bounds__(256) void k_degrees(const int* __restrict__ src, const int* __restrict__ dst){
    int e = blockIdx.x*256 + threadIdx.x;
    if (e < ECN){
        atomicAdd(&g_outdeg[clampi(src[e],0,NCN-1)],1);
        atomicAdd(&g_indeg [clampi(dst[e],0,NCN-1)],1);
    }
}

__global__ __launch_bounds__(256) void k_norms(){
    int i = blockIdx.x*256 + threadIdx.x;
    if (i < NCN){
        g_onorm[i] = rsqrtf((float)max(g_outdeg[i],1));
        g_inorm[i] = rsqrtf((float)max(g_indeg[i],1));
    }
}

// exclusive scan of indeg -> off[0..NCN]
__global__ __launch_bounds__(1024) void k_scan(){
    __shared__ int cs[1024];
    const int CH = (NCN + 1023)/1024;  // 10
    int t = threadIdx.x;
    int base = t*CH;
    int s = 0;
    for (int j=0;j<CH;j++){ int idx=base+j; if (idx<NCN) s += g_indeg[idx]; }
    cs[t] = s; __syncthreads();
    for (int ofs=1; ofs<1024; ofs<<=1){
        int v = (t>=ofs) ? cs[t-ofs] : 0;
        __syncthreads();
        cs[t] += v;
        __syncthreads();
    }
    int run = (t==0) ? 0 : cs[t-1];
    for (int j=0;j<CH;j++){
        int idx = base+j;
        if (idx <= NCN) g_off[idx] = run;
        if (idx < NCN) run += g_indeg[idx];
    }
}

__global__ __launch_bounds__(256) void k_scatter(const int* __restrict__ dst){
    int e = blockIdx.x*256 + threadIdx.x;
    if (e < ECN){
        int d = clampi(dst[e],0,NCN-1);
        int pos = g_off[d] + atomicAdd(&g_cursor[d],1);
        g_eid[clampi(pos,0,ECN-1)] = e;
    }
}

// per-node insertion sort by eid (deterministic edge order) + fill src ids
__global__ __launch_bounds__(256) void k_sortfill(const int* __restrict__ c_src){
    int d = blockIdx.x*256 + threadIdx.x;
    if (d < NCN){
        int b = clampi(g_off[d],0,ECN), e = clampi(g_off[d+1],b,ECN);
        for (int i=b+1;i<e;i++){
            int key = g_eid[i]; int j = i-1;
            while (j>=b && g_eid[j]>key){ g_eid[j+1]=g_eid[j]; j--; }
            g_eid[j+1] = key;
        }
        for (int i=b;i<e;i++) g_srcarr[i] = clampi(c_src[clampi(g_eid[i],0,ECN-1)],0,NCN-1);
    }
}

// eagg[d][f] = sum efeat, eaggR[d][f] = sum relu(efeat)  (layer-invariant)
__global__ __launch_bounds__(256) void k_eagg(const float* __restrict__ ef){
    int d = blockIdx.x*16 + threadIdx.x/16;
    int f = threadIdx.x%16;
    if (d < NCN){
        float s=0.f, sr=0.f;
        int b=clampi(g_off[d],0,ECN), e=clampi(g_off[d+1],b,ECN);
        for (int i=b;i<e;i++){
            float v = ef[(size_t)clampi(g_eid[i],0,ECN-1)*CEE + f];
            s += v; sr += fmaxf(v,0.f);
        }
        g_eagg [(size_t)d*CEE+f] = s;
        g_eaggR[(size_t)d*CEE+f] = sr;
    }
}

// ---- topo helpers: per-block edge cache + degree norms ----
__device__ __forceinline__ void topo_edges_norms(
    const int* __restrict__ t_src, const int* __restrict__ t_dst,
    int* ssrc, int* sdst, int* sdeg, float* onrm, float* inrm, int t)
{
    if (t < 2*NTT) sdeg[t]=0;
    __syncthreads();
    if (t < ETT){
        int s=clampi(t_src[t],0,NTT-1), d=clampi(t_dst[t],0,NTT-1);
        ssrc[t]=s; sdst[t]=d;
        atomicAdd(&sdeg[s],1); atomicAdd(&sdeg[NTT+d],1);
    }
    __syncthreads();
    if (t < NTT){
        onrm[t]=rsqrtf((float)max(sdeg[t],1));
        inrm[t]=rsqrtf((float)max(sdeg[NTT+t],1));
    }
    __syncthreads();
}

// ---------------- topo layer 0 (16 blocks, one per dst node) ----------------
__global__ __launch_bounds__(256) void kt_l0(
    const float* __restrict__ tfeats, const float* __restrict__ tef,
    const float* __restrict__ tW0, const float* __restrict__ tb0,
    const int* __restrict__ t_src, const int* __restrict__ t_dst)
{
    __shared__ float h[48];
    __shared__ int ssrc[ETT], sdst[ETT], sdeg[2*NTT];
    __shared__ float onrm[NTT], inrm[NTT];
    const int d = blockIdx.x, t = threadIdx.x;
    topo_edges_norms(t_src, t_dst, ssrc, sdst, sdeg, onrm, inrm, t);
    if (t < 48){
        float acc=0.f;
        for (int e=0;e<ETT;e++){
            if (sdst[e]==d){
                int s=ssrc[e];
                float v = (t<TFF) ? tfeats[s*TFF+t]*onrm[s] : tef[e*TEE+(t-TFF)];
                acc += fmaxf(v,0.f);
            }
        }
        h[t]=acc;
    }
    __syncthreads();
    float acc=0.f;
    for (int k=0;k<48;k++) acc += h[k]*tW0[k*NHH+t];
    g_tx0[d*NHH+t] = fmaxf(acc*inrm[d]+tb0[t], 0.f);
}

// ---------------- topo recurrent layer (16 blocks) ----------------
template<int DIR>  // DIR=0: tx0->tx1, DIR=1: tx1->tx0
__global__ __launch_bounds__(256) void kt_lr(
    const float* __restrict__ tef,
    const float* __restrict__ W, const float* __restrict__ bias,
    const int* __restrict__ t_src, const int* __restrict__ t_dst, int relu_res)
{
    const float* xin  = DIR ? g_tx1 : g_tx0;
    float*       xout = DIR ? g_tx0 : g_tx1;
    __shared__ float h[NHH+TEE];
    __shared__ int ssrc[ETT], sdst[ETT], sdeg[2*NTT];
    __shared__ float onrm[NTT], inrm[NTT];
    const int d = blockIdx.x, t = threadIdx.x;
    topo_edges_norms(t_src, t_dst, ssrc, sdst, sdeg, onrm, inrm, t);
    {
        float a0=0.f, a1=0.f;
        for (int e=0;e<ETT;e++){
            if (sdst[e]==d){
                a0 += xin[ssrc[e]*NHH+t]*onrm[ssrc[e]];
                if (t<TEE) a1 += tef[e*TEE+t];
            }
        }
        h[t]=a0;
        if (t<TEE) h[NHH+t]=a1;
    }
    __syncthreads();
    float acc=0.f;
    for (int k=0;k<NHH+TEE;k++) acc += h[k]*W[(size_t)k*NHH+t];
    float val = acc*inrm[d] + bias[t];
    xout[d*NHH+t] = relu_res ? (xin[d*NHH+t]*onrm[d] + fmaxf(val,0.f)) : val;
}

// v0 partial: block b computes relut row b (group sum + relu) in LDS, then GEMV slice
__global__ __launch_bounds__(256) void k_v0(const float* __restrict__ cW0, const int* __restrict__ tgroups){
    __shared__ float srt[NHH];
    int b=blockIdx.x, c=threadIdx.x;
    int i0=clampi(tgroups[b*2+0],0,NTT-1), i1=clampi(tgroups[b*2+1],0,NTT-1);
    srt[c]=fmaxf(g_tx1[i0*NHH+c]+g_tx1[i1*NHH+c],0.f);
    __syncthreads();
    const float* Wm = cW0 + (size_t)(CFF+OPEE + b*NHH)*NHH;
    float acc=0.f;
    for (int j=0;j<NHH;j++) acc += srt[j]*Wm[(size_t)j*NHH+c];
    g_v0p[b*NHH+c]=acc;
}
__global__ __launch_bounds__(256) void k_v0r(){
    int c=threadIdx.x;
    float s=0.f;
    for (int b=0;b<TGG;b++) s+=g_v0p[b*NHH+c];
    g_v0[c]=s;
}

// ---------------- cGNN layer 0 (fused gather + col-split GEMM) ----------------
// sh row layout: [0:64] cfeats | [64:68] opemb | [68] s_on | [72:88] eaggR  (width 88)
__global__ __launch_bounds__(256) void k_l0(
    const int* __restrict__ ctypes,
    const float* __restrict__ cfeats, const float* __restrict__ opemb,
    const float* __restrict__ cW0, const float* __restrict__ cb0)
{
    __shared__ float sh[NPB][88];
    const int d0 = blockIdx.x*NPB;
    const int t = threadIdx.x, lane = t & 63, q = t >> 6;

    #pragma unroll
    for (int nn=0; nn<2; ++nn){
        int n = 2*q+nn, d = d0+n;
        int b = g_off[d], e = g_off[d+1];
        float a0=0.f, a1=0.f, aon=0.f;
        for (int i=b;i<e;i++){
            int s = g_srcarr[i];
            float on = g_onorm[s];
            float cf = cfeats[(size_t)s*CFF+lane];
            a0 += fmaxf(cf,0.f)*on;
            if (lane < OPEE){
                int ct = clampi(ctypes[s],0,255);
                a1 += fmaxf(opemb[ct*OPEE+lane],0.f)*on;
            }
            aon += on;
        }
        sh[n][lane]=a0;
        if (lane<OPEE) sh[n][CFF+lane]=a1;
        if (lane==8)   sh[n][68]=aon;
    }
    if (t < NPB*CEE){ int n=t>>4, f=t&15; sh[n][72+f]=g_eaggR[(size_t)(d0+n)*CEE+f]; }
    __syncthreads();

    const int col = q*64 + lane;
    float acc[NPB];
    #pragma unroll
    for (int n=0;n<NPB;n++) acc[n]=0.f;
    // cfeats rows (64), 4 at a time
    for (int k4=0;k4<16;k4++){
        float w0=cW0[(size_t)(4*k4+0)*NHH+col];
        float w1=cW0[(size_t)(4*k4+1)*NHH+col];
        float w2=cW0[(size_t)(4*k4+2)*NHH+col];
        float w3=cW0[(size_t)(4*k4+3)*NHH+col];
        #pragma unroll
        for (int n=0;n<NPB;n++){
            float4 h4 = *((const float4*)&sh[n][4*k4]);
            acc[n] += h4.x*w0 + h4.y*w1 + h4.z*w2 + h4.w*w3;
        }
    }
    // opemb rows (4)
    #pragma unroll
    for (int k=0;k<OPEE;k++){
        float w=cW0[(size_t)(CFF+k)*NHH+col];
        #pragma unroll
        for (int n=0;n<NPB;n++) acc[n]+=sh[n][CFF+k]*w;
    }
    // collapsed t_flat block: s_on * v0
    {
        float w=g_v0[col];
        #pragma unroll
        for (int n=0;n<NPB;n++) acc[n]+=sh[n][68]*w;
    }
    // cedge rows (16), 4 at a time
    const float* We = cW0 + (size_t)(CFF+OPEE+TGG*NHH)*NHH;
    for (int f4=0;f4<4;f4++){
        float w0=We[(size_t)(4*f4+0)*NHH+col];
        float w1=We[(size_t)(4*f4+1)*NHH+col];
        float w2=We[(size_t)(4*f4+2)*NHH+col];
        float w3=We[(size_t)(4*f4+3)*NHH+col];
        #pragma unroll
        for (int n=0;n<NPB;n++){
            float4 h4 = *((const float4*)&sh[n][72+4*f4]);
            acc[n] += h4.x*w0 + h4.y*w1 + h4.z*w2 + h4.w*w3;
        }
    }
    float bb=cb0[col];
    #pragma unroll
    for (int n=0;n<NPB;n++){
        int d=d0+n;
        g_x0[(size_t)d*NHH+col]=fmaxf(acc[n]*g_inorm[d]+bb,0.f);
    }
}

// ------- recurrent layers: float4 gather + col-split GEMM (no part buffer, 8.7 KB LDS) -------
template<int DIR>   // DIR=0: x0->x1, DIR=1: x1->x0
__global__ __launch_bounds__(256) void k_layer(
    const float* __restrict__ W, const float* __restrict__ bias, int relu_res)
{
    const float* xin  = DIR ? g_x1 : g_x0;
    float*       xout = DIR ? g_x0 : g_x1;
    __shared__ float sh[NPB][NHH+CEE];   // [8][272] gathered features + eagg
    const int d0 = blockIdx.x*NPB;
    const int t = threadIdx.x, lane = t & 63, q = t >> 6;

    // gather: wave q -> nodes 2q, 2q+1; lane owns 4 consecutive cols via float4
    #pragma unroll
    for (int nn=0; nn<2; ++nn){
        int n = 2*q+nn, d = d0+n;
        int b = g_off[d], e = g_off[d+1];
        float4 a = make_float4(0.f,0.f,0.f,0.f);
        for (int i=b;i<e;i++){
            int s = g_srcarr[i];
            float on = g_onorm[s];
            const float4 v = *((const float4*)(xin + (size_t)s*NHH) + lane);
            a.x += v.x*on; a.y += v.y*on; a.z += v.z*on; a.w += v.w*on;
        }
        *((float4*)&sh[n][0] + lane) = a;
    }
    if (t < NPB*CEE){ int n=t>>4, f=t&15; sh[n][NHH+f]=g_eagg[(size_t)(d0+n)*CEE+f]; }
    __syncthreads();

    // GEMM: wave q owns cols col=64q+lane, all K=272 (4 k's per iter)
    const int col = q*64 + lane;
    float acc[NPB];
    #pragma unroll
    for (int n=0;n<NPB;n++) acc[n]=0.f;
    for (int k4=0;k4<(NHH+CEE)/4;k4++){
        float w0=W[(size_t)(4*k4+0)*NHH+col];
        float w1=W[(size_t)(4*k4+1)*NHH+col];
        float w2=W[(size_t)(4*k4+2)*NHH+col];
        float w3=W[(size_t)(4*k4+3)*NHH+col];
        #pragma unroll
        for (int n=0;n<NPB;n++){
            float4 h4 = *((const float4*)&sh[n][4*k4]);
            acc[n] += h4.x*w0 + h4.y*w1 + h4.z*w2 + h4.w*w3;
        }
    }
    float bb = bias[col];
    #pragma unroll
    for (int n=0;n<NPB;n++){
        int d = d0+n;
        float val = acc[n]*g_inorm[d]+bb;
        float y = relu_res ? (xin[(size_t)d*NHH+col]*g_onorm[d] + fmaxf(val,0.f)) : val;
        xout[(size_t)d*NHH+col]=y;
    }
}

// ---------------- pooling (4 deterministic partials per group) + heads ----------------
__global__ __launch_bounds__(256) void k_cemb(const int* __restrict__ cgroups){
    int g=blockIdx.x>>2, p=blockIdx.x&3, c=threadIdx.x;
    float s=0.f;
    for (int i=p*25;i<p*25+25;i++){
        int idx=clampi(cgroups[g*GSZ+i],0,NCN-1);
        s += g_x1[(size_t)idx*NHH+c];
    }
    g_cembp[(size_t)(p*GCN+g)*NHH+c]=s;
}

__global__ __launch_bounds__(256) void k_heads(
    const float* __restrict__ sW, const float* __restrict__ sb,
    const float* __restrict__ nW, const float* __restrict__ nb, float* __restrict__ out)
{
    __shared__ float red[256];
    __shared__ float z[9];
    int g=blockIdx.x, t=threadIdx.x;
    float e = g_cembp[(size_t)(0*GCN+g)*NHH+t] + g_cembp[(size_t)(1*GCN+g)*NHH+t]
            + g_cembp[(size_t)(2*GCN+g)*NHH+t] + g_cembp[(size_t)(3*GCN+g)*NHH+t];
    for (int j=0;j<9;j++){
        float w = (j==0) ? nW[t] : sW[t*TGG+(j-1)];
        red[t]=e*w; __syncthreads();
        for (int s=128;s>0;s>>=1){ if (t<s) red[t]+=red[t+s]; __syncthreads(); }
        if (t==0) z[j]=red[0];
        __syncthreads();
    }
    if (t==0){
        float z0 = z[0] + nb[0];
        float lsig = fminf(z0,0.f) - log1pf(expf(-fabsf(z0)));
        out[g*9+0]=lsig;
        float zz[8]; float m=-1e30f;
        for (int j=0;j<8;j++){ zz[j]=z[j+1]+sb[j]; m=fmaxf(m,zz[j]); }
        float s=0.f;
        for (int j=0;j<8;j++) s+=expf(zz[j]-m);
        float lse=m+logf(s);
        for (int j=0;j<8;j++) out[g*9+1+j]=zz[j]-lse;
    }
}

extern "C" void kernel_launch(void* const* d_in, const int* in_sizes, int n_in,
                              void* d_out, int out_size, void* d_ws, size_t ws_size,
                              hipStream_t stream) {
    const int expect[24] = {
        NCN*CFF, ECN*CEE, NTT*TFF, ETT*TEE, 256*OPEE,
        (TFF+TEE)*NHH, NHH, 3*(NHH+TEE)*NHH, 3*NHH,
        (CFF+OPEE+TGG*NHH+CEE)*NHH, NHH, 5*(NHH+CEE)*NHH, 5*NHH,
        NHH*TGG, TGG, NHH, 1,
        NCN, ECN, ECN, ETT, ETT, GCN*GSZ, TGG*2
    };
    if (n_in < 24){
        k_badsize<<<(out_size+255)/256,256,0,stream>>>((float*)d_out, out_size, 2.0e6f);
        return;
    }
    for (int i=0;i<24;i++){
        if (in_sizes[i] != expect[i]){
            k_badsize<<<(out_size+255)/256,256,0,stream>>>((float*)d_out, out_size, 1.0e6f+(float)i);
            return;
        }
    }

    const float* cfeats = (const float*)d_in[0];
    const float* cef    = (const float*)d_in[1];
    const float* tfeats = (const float*)d_in[2];
    const float* tef    = (const float*)d_in[3];
    const float* opemb  = (const float*)d_in[4];
    const float* tW0    = (const float*)d_in[5];
    const float* tb0    = (const float*)d_in[6];
    const float* tWr    = (const float*)d_in[7];
    const float* tbr    = (const float*)d_in[8];
    const float* cW0    = (const float*)d_in[9];
    const float* cb0    = (const float*)d_in[10];
    const float* cWr    = (const float*)d_in[11];
    const float* cbr    = (const float*)d_in[12];
    const float* sW     = (const float*)d_in[13];
    const float* sb     = (const float*)d_in[14];
    const float* nW     = (const float*)d_in[15];
    const float* nb     = (const float*)d_in[16];
    const int* ctypes   = (const int*)d_in[17];
    const int* c_src    = (const int*)d_in[18];
    const int* c_dst    = (const int*)d_in[19];
    const int* t_src    = (const int*)d_in[20];
    const int* t_dst    = (const int*)d_in[21];
    const int* cgroups  = (const int*)d_in[22];
    const int* tgroups  = (const int*)d_in[23];

    const int EB = (ECN+255)/256, NB = (NCN+255)/256;

    k_zero3   <<<NB, 256, 0, stream>>>();
    k_degrees <<<EB, 256, 0, stream>>>(c_src, c_dst);
    k_norms   <<<NB, 256, 0, stream>>>();
    k_scan    <<<1, 1024, 0, stream>>>();
    k_scatter <<<EB, 256, 0, stream>>>(c_dst);
    k_sortfill<<<NB, 256, 0, stream>>>(c_src);
    k_eagg    <<<(NCN+15)/16, 256, 0, stream>>>(cef);

    // topo GNN: 16-block per-layer kernels, ping-pong tx0/tx1 (final in tx1)
    kt_l0    <<<NTT, 256, 0, stream>>>(tfeats, tef, tW0, tb0, t_src, t_dst);
    kt_lr<0> <<<NTT, 256, 0, stream>>>(tef, tWr + (size_t)0*(NHH+TEE)*NHH, tbr + 0*NHH, t_src, t_dst, 1);
    kt_lr<1> <<<NTT, 256, 0, stream>>>(tef, tWr + (size_t)1*(NHH+TEE)*NHH, tbr + 1*NHH, t_src, t_dst, 1);
    kt_lr<0> <<<NTT, 256, 0, stream>>>(tef, tWr + (size_t)2*(NHH+TEE)*NHH, tbr + 2*NHH, t_src, t_dst, 0);
    k_v0     <<<TGG, 256, 0, stream>>>(cW0, tgroups);
    k_v0r    <<<1, 256, 0, stream>>>();

    k_l0     <<<NCN/NPB, 256, 0, stream>>>(ctypes, cfeats, opemb, cW0, cb0);

    // 5 recurrent layers: x0 -> x1 -> x0 -> x1 -> x0 -> x1  (final in g_x1)
    k_layer<0><<<NCN/NPB, 256, 0, stream>>>(cWr + (size_t)0*(NHH+CEE)*NHH, cbr + 0*NHH, 1);
    k_layer<1><<<NCN/NPB, 256, 0, stream>>>(cWr + (size_t)1*(NHH+CEE)*NHH, cbr + 1*NHH, 1);
    k_layer<0><<<NCN/NPB, 256, 0, stream>>>(cWr + (size_t)2*(NHH+CEE)*NHH, cbr + 2*NHH, 1);
    k_layer<1><<<NCN/NPB, 256, 0, stream>>>(cWr + (size_t)3*(NHH+CEE)*NHH, cbr + 3*NHH, 1);
    k_layer<0><<<NCN/NPB, 256, 0, stream>>>(cWr + (size_t)4*(NHH+CEE)*NHH, cbr + 4*NHH, 0);

    k_cemb <<<4*GCN, 256, 0, stream>>>(cgroups);
    k_heads<<<GCN, 256, 0, stream>>>(sW, sb, nW, nb, (float*)d_out);
}